// Round 3
// baseline (3897.092 us; speedup 1.0000x reference)
//
#include <hip/hip_runtime.h>
#include <hip/hip_bf16.h>

#define B_SZ 4
#define T_SEQ 2048
#define NH 16
#define DK 64
#define DM 1024

typedef __bf16 bf16x8 __attribute__((ext_vector_type(8)));
typedef float floatx4 __attribute__((ext_vector_type(4)));

// fp32 -> bf16 canonicalization (inputs are fp32 per reference; MFMA wants bf16)
__global__ __launch_bounds__(256) void convert_kernel(const float* __restrict__ src,
                                                      __hip_bfloat16* __restrict__ dst,
                                                      int n)
{
    const int stride = gridDim.x * 256;
    for (int i = blockIdx.x * 256 + threadIdx.x; i < n; i += stride)
        dst[i] = __float2bfloat16(src[i]);
}

// ---------------------------------------------------------------------------
// C[m][n] = sum_k A[m][k] * W[n][k]   (A: [8192][1024], W: [1024][1024], K-contig)
// mode 0: dst_f32[m*1024 + n]   (row-major fp32, O-proj -> d_out)
// mode 1: dst_bf16[((b*NH+h)*T + t)*DK + d]  (QKV layout, bf16)
// ---------------------------------------------------------------------------
__global__ __launch_bounds__(256) void gemm16_kernel(const __bf16* __restrict__ A,
                                                     const __bf16* __restrict__ W,
                                                     __hip_bfloat16* __restrict__ dst_bf16,
                                                     float* __restrict__ dst_f32,
                                                     int mode)
{
    const int lane   = threadIdx.x & 63;
    const int wave   = blockIdx.x * 4 + (threadIdx.x >> 6);   // 32768 waves
    const int tile_n = wave & 63;
    const int tile_m = wave >> 6;

    const int m    = tile_m * 16 + (lane & 15);
    const int n    = tile_n * 16 + (lane & 15);
    const int ksub = (lane >> 4) * 8;

    const __bf16* Ar = A + (size_t)m * DM + ksub;
    const __bf16* Wr = W + (size_t)n * DM + ksub;

    floatx4 acc = {0.f, 0.f, 0.f, 0.f};
    #pragma unroll 8
    for (int k0 = 0; k0 < DM; k0 += 32) {
        bf16x8 a = *(const bf16x8*)(Ar + k0);
        bf16x8 b = *(const bf16x8*)(Wr + k0);
        acc = __builtin_amdgcn_mfma_f32_16x16x32_bf16(a, b, acc, 0, 0, 0);
    }

    const int col  = tile_n * 16 + (lane & 15);
    const int row0 = tile_m * 16 + (lane >> 4) * 4;
    #pragma unroll
    for (int r = 0; r < 4; ++r) {
        const int row = row0 + r;
        const float v = acc[r];
        if (mode == 0) {
            dst_f32[(size_t)row * DM + col] = v;
        } else {
            const int b = row >> 11, t = row & (T_SEQ - 1);
            const int h = col >> 6,  d = col & (DK - 1);
            dst_bf16[(((size_t)(b * NH + h)) * T_SEQ + t) * DK + d] = __float2bfloat16(v);
        }
    }
}

// In-place RoPE on Q and K, layout [B][NH][T][DK]. One thread per (b,h,t,pair).
__global__ __launch_bounds__(256) void rope_kernel(__hip_bfloat16* __restrict__ Q,
                                                   __hip_bfloat16* __restrict__ K,
                                                   const int* __restrict__ tp)
{
    const int idx = blockIdx.x * 256 + threadIdx.x;   // 4*16*2048*32 = 4194304
    const int f = idx & 31;
    const int t = (idx >> 5) & (T_SEQ - 1);
    const int h = (idx >> 16) & (NH - 1);
    const int b = idx >> 20;

    const int pos = tp[b * T_SEQ + t];
    const float inv = powf(10000.0f, -(float)f / 32.0f);   // theta^(-2f/64)
    const float ang = (float)pos * inv;
    float s, c;
    sincosf(ang, &s, &c);

    const size_t off = (((size_t)(b * NH + h)) * T_SEQ + t) * DK + 2 * f;
    const float q0 = __bfloat162float(Q[off]);
    const float q1 = __bfloat162float(Q[off + 1]);
    Q[off]     = __float2bfloat16(q0 * c - q1 * s);
    Q[off + 1] = __float2bfloat16(q1 * c + q0 * s);
    const float k0 = __bfloat162float(K[off]);
    const float k1 = __bfloat162float(K[off + 1]);
    K[off]     = __float2bfloat16(k0 * c - k1 * s);
    K[off + 1] = __float2bfloat16(k1 * c + k0 * s);
}

// One wave per (b,h,ti) query row. Online softmax over tj chunks of 64. fp32 state.
__global__ __launch_bounds__(256) void attn_kernel(const __hip_bfloat16* __restrict__ Q,
                                                   const __hip_bfloat16* __restrict__ K,
                                                   const __hip_bfloat16* __restrict__ V,
                                                   __hip_bfloat16* __restrict__ O)
{
    __shared__ float sh_q[4][DK];
    __shared__ float sh_p[4][DK];

    const int wv   = threadIdx.x >> 6;
    const int lane = threadIdx.x & 63;
    const int w    = blockIdx.x * 4 + wv;       // B*NH*T waves
    const int bh   = w >> 11;
    const int ti   = w & (T_SEQ - 1);
    const int b    = bh >> 4, h = bh & (NH - 1);

    const __hip_bfloat16* Qr = Q + (((size_t)bh * T_SEQ) + ti) * DK;
    const __hip_bfloat16* Kb = K + ((size_t)bh * T_SEQ) * DK;
    const __hip_bfloat16* Vb = V + ((size_t)bh * T_SEQ) * DK;

    sh_q[wv][lane] = __bfloat162float(Qr[lane]) * 0.125f;   // pre-scaled q
    __builtin_amdgcn_wave_barrier();

    float m_run = -1e30f;
    float l_run = 0.f;
    float acc   = 0.f;   // lane owns output dim d = lane

    for (int base = 0; base <= ti; base += 64) {
        const int tj = base + lane;
        const bool valid = (tj <= ti);
        const int tjc = valid ? tj : ti;

        const __hip_bfloat162* kr = (const __hip_bfloat162*)(Kb + (size_t)tjc * DK);
        float dot = 0.f;
        #pragma unroll
        for (int j = 0; j < 32; ++j) {
            const float2 kv = __bfloat1622float2(kr[j]);
            dot += sh_q[wv][2 * j] * kv.x + sh_q[wv][2 * j + 1] * kv.y;
        }
        const float s = valid ? dot : -1e30f;

        float mx = s;
        #pragma unroll
        for (int off = 1; off < 64; off <<= 1) mx = fmaxf(mx, __shfl_xor(mx, off));
        const float new_m = fmaxf(m_run, mx);
        const float alpha = __expf(m_run - new_m);
        const float p = valid ? __expf(s - new_m) : 0.f;

        sh_p[wv][lane] = p;
        __builtin_amdgcn_wave_barrier();

        float ps = p;
        #pragma unroll
        for (int off = 1; off < 64; off <<= 1) ps += __shfl_xor(ps, off);
        l_run = l_run * alpha + ps;
        acc *= alpha;

        const int nv = min(64, ti - base + 1);
        for (int j = 0; j < nv; ++j) {
            const float pj = sh_p[wv][j];
            acc += pj * __bfloat162float(Vb[(size_t)(base + j) * DK + lane]);
        }
        __builtin_amdgcn_wave_barrier();
        m_run = new_m;
    }

    const float out = acc / l_run;
    O[(((size_t)b * T_SEQ) + ti) * DM + h * DK + lane] = __float2bfloat16(out);
}

extern "C" void kernel_launch(void* const* d_in, const int* in_sizes, int n_in,
                              void* d_out, int out_size, void* d_ws, size_t ws_size,
                              hipStream_t stream) {
    const float* x  = (const float*)d_in[0];
    const int*   tp = (const int*)d_in[1];
    const float* wq = (const float*)d_in[2];
    const float* wk = (const float*)d_in[3];
    const float* wv = (const float*)d_in[4];
    const float* wo = (const float*)d_in[5];

    char* ws = (char*)d_ws;
    const size_t XSZ = (size_t)B_SZ * T_SEQ * DM * 2;       // 16.78 MB
    const size_t WSZ = (size_t)DM * DM * 2;                 // 2 MB
    const size_t SZ  = (size_t)B_SZ * NH * T_SEQ * DK * 2;  // 16.78 MB

    __hip_bfloat16* xb  = (__hip_bfloat16*)(ws);
    __hip_bfloat16* wqb = (__hip_bfloat16*)(ws + XSZ);
    __hip_bfloat16* wkb = (__hip_bfloat16*)(ws + XSZ + WSZ);
    __hip_bfloat16* wvb = (__hip_bfloat16*)(ws + XSZ + 2 * WSZ);
    __hip_bfloat16* wob = (__hip_bfloat16*)(ws + XSZ + 3 * WSZ);
    __hip_bfloat16* Q   = (__hip_bfloat16*)(ws + XSZ + 4 * WSZ);
    __hip_bfloat16* K   = (__hip_bfloat16*)(ws + XSZ + 4 * WSZ + SZ);
    __hip_bfloat16* V   = (__hip_bfloat16*)(ws + XSZ + 4 * WSZ + 2 * SZ);
    __hip_bfloat16* AO  = (__hip_bfloat16*)(ws + XSZ + 4 * WSZ + 3 * SZ);
    float* out = (float*)d_out;

    // 1. canonicalize fp32 inputs to bf16
    convert_kernel<<<2048, 256, 0, stream>>>(x,  xb,  B_SZ * T_SEQ * DM);
    convert_kernel<<<512,  256, 0, stream>>>(wq, wqb, DM * DM);
    convert_kernel<<<512,  256, 0, stream>>>(wk, wkb, DM * DM);
    convert_kernel<<<512,  256, 0, stream>>>(wv, wvb, DM * DM);
    convert_kernel<<<512,  256, 0, stream>>>(wo, wob, DM * DM);

    // 2. QKV projections (MFMA bf16) -> [B][H][T][DK]
    gemm16_kernel<<<8192, 256, 0, stream>>>((const __bf16*)xb, (const __bf16*)wqb, Q, nullptr, 1);
    gemm16_kernel<<<8192, 256, 0, stream>>>((const __bf16*)xb, (const __bf16*)wkb, K, nullptr, 1);
    gemm16_kernel<<<8192, 256, 0, stream>>>((const __bf16*)xb, (const __bf16*)wvb, V, nullptr, 1);

    // 3. RoPE in place on Q, K
    rope_kernel<<<16384, 256, 0, stream>>>(Q, K, tp);

    // 4. causal attention with online softmax -> AO [B][T][DM] (bf16)
    attn_kernel<<<32768, 256, 0, stream>>>(Q, K, V, AO);

    // 5. O projection -> d_out (fp32, the reference's output dtype)
    gemm16_kernel<<<8192, 256, 0, stream>>>((const __bf16*)AO, (const __bf16*)wob, nullptr, out, 0);
}

// Round 4
// 1482.660 us; speedup vs baseline: 2.6284x; 2.6284x over previous
//
#include <hip/hip_runtime.h>
#include <hip/hip_bf16.h>

#define B_SZ 4
#define T_SEQ 2048
#define NH 16
#define DK 64
#define DM 1024

typedef __bf16 bf16x8 __attribute__((ext_vector_type(8)));
typedef float floatx4 __attribute__((ext_vector_type(4)));

// fp32 -> bf16 canonicalization
__global__ __launch_bounds__(256) void convert_kernel(const float* __restrict__ src,
                                                      __hip_bfloat16* __restrict__ dst,
                                                      int n)
{
    const int stride = gridDim.x * 256;
    for (int i = blockIdx.x * 256 + threadIdx.x; i < n; i += stride)
        dst[i] = __float2bfloat16(src[i]);
}

// ---------------------------------------------------------------------------
// C[m][n] = sum_k A[m][k] * W[n][k]   (A: [8192][1024], W: [1024][1024], K-contig)
// mode 0: dst_f32[m*1024 + n]                     (row-major fp32, O-proj -> d_out)
// mode 1: dst_bf16[((b*NH+h)*T + t)*DK + d]       (QK layout, bf16)
// mode 2: dst_bf16[((b*NH+h)*DK + d)*T + t]       (V transposed for flash PV B-operand)
// ---------------------------------------------------------------------------
__global__ __launch_bounds__(256) void gemm16_kernel(const __bf16* __restrict__ A,
                                                     const __bf16* __restrict__ W,
                                                     __hip_bfloat16* __restrict__ dst_bf16,
                                                     float* __restrict__ dst_f32,
                                                     int mode)
{
    const int lane   = threadIdx.x & 63;
    const int wave   = blockIdx.x * 4 + (threadIdx.x >> 6);   // 32768 waves
    const int tile_n = wave & 63;
    const int tile_m = wave >> 6;

    const int m    = tile_m * 16 + (lane & 15);
    const int n    = tile_n * 16 + (lane & 15);
    const int ksub = (lane >> 4) * 8;

    const __bf16* Ar = A + (size_t)m * DM + ksub;
    const __bf16* Wr = W + (size_t)n * DM + ksub;

    floatx4 acc = {0.f, 0.f, 0.f, 0.f};
    #pragma unroll 8
    for (int k0 = 0; k0 < DM; k0 += 32) {
        bf16x8 a = *(const bf16x8*)(Ar + k0);
        bf16x8 b = *(const bf16x8*)(Wr + k0);
        acc = __builtin_amdgcn_mfma_f32_16x16x32_bf16(a, b, acc, 0, 0, 0);
    }

    const int col  = tile_n * 16 + (lane & 15);
    const int row0 = tile_m * 16 + (lane >> 4) * 4;
    #pragma unroll
    for (int r = 0; r < 4; ++r) {
        const int row = row0 + r;
        const float v = acc[r];
        if (mode == 0) {
            dst_f32[(size_t)row * DM + col] = v;
        } else if (mode == 1) {
            const int b = row >> 11, t = row & (T_SEQ - 1);
            const int h = col >> 6,  d = col & (DK - 1);
            dst_bf16[(((size_t)(b * NH + h)) * T_SEQ + t) * DK + d] = __float2bfloat16(v);
        } else {
            const int b = row >> 11, t = row & (T_SEQ - 1);
            const int h = col >> 6,  d = col & (DK - 1);
            dst_bf16[(((size_t)(b * NH + h)) * DK + d) * T_SEQ + t] = __float2bfloat16(v);
        }
    }
}

// In-place RoPE on Q and K, layout [B][NH][T][DK]. Q additionally scaled by 1/8
// (1/sqrt(dk), exact in bf16) so the attention kernel skips the scale.
__global__ __launch_bounds__(256) void rope_kernel(__hip_bfloat16* __restrict__ Q,
                                                   __hip_bfloat16* __restrict__ K,
                                                   const int* __restrict__ tp)
{
    const int idx = blockIdx.x * 256 + threadIdx.x;   // 4*16*2048*32 = 4194304
    const int f = idx & 31;
    const int t = (idx >> 5) & (T_SEQ - 1);
    const int h = (idx >> 16) & (NH - 1);
    const int b = idx >> 20;

    const int pos = tp[b * T_SEQ + t];
    const float inv = powf(10000.0f, -(float)f / 32.0f);   // theta^(-2f/64)
    const float ang = (float)pos * inv;
    float s, c;
    sincosf(ang, &s, &c);

    const size_t off = (((size_t)(b * NH + h)) * T_SEQ + t) * DK + 2 * f;
    const float q0 = __bfloat162float(Q[off]);
    const float q1 = __bfloat162float(Q[off + 1]);
    Q[off]     = __float2bfloat16((q0 * c - q1 * s) * 0.125f);
    Q[off + 1] = __float2bfloat16((q1 * c + q0 * s) * 0.125f);
    const float k0 = __bfloat162float(K[off]);
    const float k1 = __bfloat162float(K[off + 1]);
    K[off]     = __float2bfloat16(k0 * c - k1 * s);
    K[off + 1] = __float2bfloat16(k1 * c + k0 * s);
}

// ---------------------------------------------------------------------------
// Flash attention: one wave per 16-row Q tile, online softmax, MFMA QK^T + PV.
// Q (pre-scaled), K: [B][NH][T][DK] bf16.  VT: [B][NH][DK][T] bf16.
// AO: [B][T][DM] bf16.
// ---------------------------------------------------------------------------
__global__ __launch_bounds__(256) void fattn_kernel(const __bf16* __restrict__ Q,
                                                    const __bf16* __restrict__ K,
                                                    const __bf16* __restrict__ VT,
                                                    __hip_bfloat16* __restrict__ AO)
{
    // P round-trip buffer, one per wave; row stride 40 (=80B) keeps b128 reads
    // at <=2-way bank aliasing (free) and 16B alignment.
    __shared__ __align__(16) __hip_bfloat16 sh_p[4][16][40];

    const int wv   = threadIdx.x >> 6;
    const int lane = threadIdx.x & 63;
    const int l16  = lane & 15;
    const int quad = lane >> 4;
    const int w    = blockIdx.x * 4 + wv;       // 8192 waves
    const int tile = w & 127;
    const int bh   = w >> 7;
    const int b    = bh >> 4, h = bh & (NH - 1);
    const int qi0  = tile * 16;

    // Q fragments (A-operand): lane holds Q[qi0 + l16][quad*8 + j (+32)]
    const __bf16* Qp = Q + ((size_t)bh * T_SEQ + qi0 + l16) * DK + quad * 8;
    const bf16x8 qa0 = *(const bf16x8*)Qp;
    const bf16x8 qa1 = *(const bf16x8*)(Qp + 32);

    const __bf16* Kb = K  + (size_t)bh * T_SEQ * DK;
    const __bf16* Vb = VT + (size_t)bh * DK * T_SEQ;

    floatx4 o0 = {0,0,0,0}, o1 = {0,0,0,0}, o2 = {0,0,0,0}, o3 = {0,0,0,0};
    float m_run[4] = {-1e30f, -1e30f, -1e30f, -1e30f};
    float l_run[4] = {0.f, 0.f, 0.f, 0.f};

    const int nch = (qi0 + 47) >> 5;            // 32-wide KV chunks, causal
    for (int c = 0; c < nch; ++c) {
        const int tj0 = c * 32;

        // K fragments (B-operand = K rows, K-contiguous)
        const __bf16* kp = Kb + (size_t)(tj0 + l16) * DK + quad * 8;
        const bf16x8 kb0l = *(const bf16x8*)kp;
        const bf16x8 kb0h = *(const bf16x8*)(kp + 32);
        const bf16x8 kb1l = *(const bf16x8*)(kp + 16 * DK);
        const bf16x8 kb1h = *(const bf16x8*)(kp + 16 * DK + 32);

        floatx4 s0 = {0,0,0,0}, s1 = {0,0,0,0};
        s0 = __builtin_amdgcn_mfma_f32_16x16x32_bf16(qa0, kb0l, s0, 0, 0, 0);
        s0 = __builtin_amdgcn_mfma_f32_16x16x32_bf16(qa1, kb0h, s0, 0, 0, 0);
        s1 = __builtin_amdgcn_mfma_f32_16x16x32_bf16(qa0, kb1l, s1, 0, 0, 0);
        s1 = __builtin_amdgcn_mfma_f32_16x16x32_bf16(qa1, kb1h, s1, 0, 0, 0);

        // online softmax; C-layout: col = l16 (+16 for s1), row = quad*4 + r
        float p0[4], p1[4], al[4];
        #pragma unroll
        for (int r = 0; r < 4; ++r) {
            const int qi = qi0 + quad * 4 + r;
            const float v0 = (tj0 + l16      <= qi) ? s0[r] : -1e30f;
            const float v1 = (tj0 + 16 + l16 <= qi) ? s1[r] : -1e30f;
            float mt = fmaxf(v0, v1);
            mt = fmaxf(mt, __shfl_xor(mt, 1));
            mt = fmaxf(mt, __shfl_xor(mt, 2));
            mt = fmaxf(mt, __shfl_xor(mt, 4));
            mt = fmaxf(mt, __shfl_xor(mt, 8));
            const float nm = fmaxf(m_run[r], mt);
            al[r] = __expf(m_run[r] - nm);
            m_run[r] = nm;
            p0[r] = __expf(v0 - nm);
            p1[r] = __expf(v1 - nm);
            float ps = p0[r] + p1[r];
            ps += __shfl_xor(ps, 1);
            ps += __shfl_xor(ps, 2);
            ps += __shfl_xor(ps, 4);
            ps += __shfl_xor(ps, 8);
            l_run[r] = l_run[r] * al[r] + ps;
        }

        // rescale O, stash P into LDS (C-layout -> A-layout transform)
        #pragma unroll
        for (int r = 0; r < 4; ++r) {
            o0[r] *= al[r]; o1[r] *= al[r]; o2[r] *= al[r]; o3[r] *= al[r];
            sh_p[wv][quad * 4 + r][l16]      = __float2bfloat16(p0[r]);
            sh_p[wv][quad * 4 + r][16 + l16] = __float2bfloat16(p1[r]);
        }
        asm volatile("s_waitcnt lgkmcnt(0)" ::: "memory");
        __builtin_amdgcn_wave_barrier();

        // P as A-operand: lane holds P[l16][quad*8 + j]
        const bf16x8 pa = *(const bf16x8*)&sh_p[wv][l16][quad * 8];

        // PV: B-operand from VT (contiguous in t)
        const __bf16* vp = Vb + (size_t)l16 * T_SEQ + tj0 + quad * 8;
        o0 = __builtin_amdgcn_mfma_f32_16x16x32_bf16(pa, *(const bf16x8*)vp,                 o0, 0, 0, 0);
        o1 = __builtin_amdgcn_mfma_f32_16x16x32_bf16(pa, *(const bf16x8*)(vp + 16 * T_SEQ), o1, 0, 0, 0);
        o2 = __builtin_amdgcn_mfma_f32_16x16x32_bf16(pa, *(const bf16x8*)(vp + 32 * T_SEQ), o2, 0, 0, 0);
        o3 = __builtin_amdgcn_mfma_f32_16x16x32_bf16(pa, *(const bf16x8*)(vp + 48 * T_SEQ), o3, 0, 0, 0);
        __builtin_amdgcn_wave_barrier();
    }

    float inv[4];
    #pragma unroll
    for (int r = 0; r < 4; ++r) inv[r] = 1.0f / l_run[r];

    __hip_bfloat16* Ao = AO + ((size_t)b * T_SEQ + qi0 + quad * 4) * DM + h * 64 + l16;
    #pragma unroll
    for (int r = 0; r < 4; ++r) {
        Ao[(size_t)r * DM +  0] = __float2bfloat16(o0[r] * inv[r]);
        Ao[(size_t)r * DM + 16] = __float2bfloat16(o1[r] * inv[r]);
        Ao[(size_t)r * DM + 32] = __float2bfloat16(o2[r] * inv[r]);
        Ao[(size_t)r * DM + 48] = __float2bfloat16(o3[r] * inv[r]);
    }
}

extern "C" void kernel_launch(void* const* d_in, const int* in_sizes, int n_in,
                              void* d_out, int out_size, void* d_ws, size_t ws_size,
                              hipStream_t stream) {
    const float* x  = (const float*)d_in[0];
    const int*   tp = (const int*)d_in[1];
    const float* wq = (const float*)d_in[2];
    const float* wk = (const float*)d_in[3];
    const float* wv = (const float*)d_in[4];
    const float* wo = (const float*)d_in[5];

    char* ws = (char*)d_ws;
    const size_t XSZ = (size_t)B_SZ * T_SEQ * DM * 2;       // 16.78 MB
    const size_t WSZ = (size_t)DM * DM * 2;                 // 2 MB
    const size_t SZ  = (size_t)B_SZ * NH * T_SEQ * DK * 2;  // 16.78 MB

    __hip_bfloat16* xb  = (__hip_bfloat16*)(ws);
    __hip_bfloat16* wqb = (__hip_bfloat16*)(ws + XSZ);
    __hip_bfloat16* wkb = (__hip_bfloat16*)(ws + XSZ + WSZ);
    __hip_bfloat16* wvb = (__hip_bfloat16*)(ws + XSZ + 2 * WSZ);
    __hip_bfloat16* wob = (__hip_bfloat16*)(ws + XSZ + 3 * WSZ);
    __hip_bfloat16* Q   = (__hip_bfloat16*)(ws + XSZ + 4 * WSZ);
    __hip_bfloat16* K   = (__hip_bfloat16*)(ws + XSZ + 4 * WSZ + SZ);
    __hip_bfloat16* VT  = (__hip_bfloat16*)(ws + XSZ + 4 * WSZ + 2 * SZ);
    __hip_bfloat16* AO  = (__hip_bfloat16*)(ws + XSZ + 4 * WSZ + 3 * SZ);
    float* out = (float*)d_out;

    // 1. canonicalize fp32 inputs to bf16
    convert_kernel<<<2048, 256, 0, stream>>>(x,  xb,  B_SZ * T_SEQ * DM);
    convert_kernel<<<512,  256, 0, stream>>>(wq, wqb, DM * DM);
    convert_kernel<<<512,  256, 0, stream>>>(wk, wkb, DM * DM);
    convert_kernel<<<512,  256, 0, stream>>>(wv, wvb, DM * DM);
    convert_kernel<<<512,  256, 0, stream>>>(wo, wob, DM * DM);

    // 2. projections: Q,K -> [B][H][T][DK]; V -> transposed [B][H][DK][T]
    gemm16_kernel<<<8192, 256, 0, stream>>>((const __bf16*)xb, (const __bf16*)wqb, Q,  nullptr, 1);
    gemm16_kernel<<<8192, 256, 0, stream>>>((const __bf16*)xb, (const __bf16*)wkb, K,  nullptr, 1);
    gemm16_kernel<<<8192, 256, 0, stream>>>((const __bf16*)xb, (const __bf16*)wvb, VT, nullptr, 2);

    // 3. RoPE in place on Q (scaled by 1/8), K
    rope_kernel<<<16384, 256, 0, stream>>>(Q, K, tp);

    // 4. flash attention -> AO [B][T][DM] (bf16)
    fattn_kernel<<<2048, 256, 0, stream>>>((const __bf16*)Q, (const __bf16*)K,
                                           (const __bf16*)VT, AO);

    // 5. O projection -> d_out (fp32)
    gemm16_kernel<<<8192, 256, 0, stream>>>((const __bf16*)AO, (const __bf16*)wob, nullptr, out, 0);
}

// Round 5
// 1276.353 us; speedup vs baseline: 3.0533x; 1.1616x over previous
//
#include <hip/hip_runtime.h>
#include <hip/hip_bf16.h>

#define B_SZ 4
#define T_SEQ 2048
#define NH 16
#define DK 64
#define DM 1024

typedef __bf16 bf16x8 __attribute__((ext_vector_type(8)));
typedef __bf16 bf16x4 __attribute__((ext_vector_type(4)));
typedef float floatx4 __attribute__((ext_vector_type(4)));

// fp32 -> bf16 canonicalization
__global__ __launch_bounds__(256) void convert_kernel(const float* __restrict__ src,
                                                      __hip_bfloat16* __restrict__ dst,
                                                      int n)
{
    const int stride = gridDim.x * 256;
    for (int i = blockIdx.x * 256 + threadIdx.x; i < n; i += stride)
        dst[i] = __float2bfloat16(src[i]);
}

// ---------------------------------------------------------------------------
// C[m][n] = sum_k A[m][k] * W[n][k]   (A: [8192][1024], W: [1024][1024], K-contig)
// mode 0: dst_f32[m*1024 + n]                     (row-major fp32, O-proj -> d_out)
// mode 1: dst_bf16[((b*NH+h)*T + t)*DK + d]       (QK layout, bf16)
// mode 2: dst_bf16[((b*NH+h)*DK + d)*T + t]       (V transposed for flash PV A-operand)
// ---------------------------------------------------------------------------
__global__ __launch_bounds__(256) void gemm16_kernel(const __bf16* __restrict__ A,
                                                     const __bf16* __restrict__ W,
                                                     __hip_bfloat16* __restrict__ dst_bf16,
                                                     float* __restrict__ dst_f32,
                                                     int mode)
{
    const int lane   = threadIdx.x & 63;
    const int wave   = blockIdx.x * 4 + (threadIdx.x >> 6);   // 32768 waves
    const int tile_n = wave & 63;
    const int tile_m = wave >> 6;

    const int m    = tile_m * 16 + (lane & 15);
    const int n    = tile_n * 16 + (lane & 15);
    const int ksub = (lane >> 4) * 8;

    const __bf16* Ar = A + (size_t)m * DM + ksub;
    const __bf16* Wr = W + (size_t)n * DM + ksub;

    floatx4 acc = {0.f, 0.f, 0.f, 0.f};
    #pragma unroll 8
    for (int k0 = 0; k0 < DM; k0 += 32) {
        bf16x8 a = *(const bf16x8*)(Ar + k0);
        bf16x8 b = *(const bf16x8*)(Wr + k0);
        acc = __builtin_amdgcn_mfma_f32_16x16x32_bf16(a, b, acc, 0, 0, 0);
    }

    const int col  = tile_n * 16 + (lane & 15);
    const int row0 = tile_m * 16 + (lane >> 4) * 4;
    #pragma unroll
    for (int r = 0; r < 4; ++r) {
        const int row = row0 + r;
        const float v = acc[r];
        if (mode == 0) {
            dst_f32[(size_t)row * DM + col] = v;
        } else if (mode == 1) {
            const int b = row >> 11, t = row & (T_SEQ - 1);
            const int h = col >> 6,  d = col & (DK - 1);
            dst_bf16[(((size_t)(b * NH + h)) * T_SEQ + t) * DK + d] = __float2bfloat16(v);
        } else {
            const int b = row >> 11, t = row & (T_SEQ - 1);
            const int h = col >> 6,  d = col & (DK - 1);
            dst_bf16[(((size_t)(b * NH + h)) * DK + d) * T_SEQ + t] = __float2bfloat16(v);
        }
    }
}

// In-place RoPE on Q and K, layout [B][NH][T][DK]. Q additionally scaled by 1/8.
__global__ __launch_bounds__(256) void rope_kernel(__hip_bfloat16* __restrict__ Q,
                                                   __hip_bfloat16* __restrict__ K,
                                                   const int* __restrict__ tp)
{
    const int idx = blockIdx.x * 256 + threadIdx.x;   // 4*16*2048*32 = 4194304
    const int f = idx & 31;
    const int t = (idx >> 5) & (T_SEQ - 1);
    const int h = (idx >> 16) & (NH - 1);
    const int b = idx >> 20;

    const int pos = tp[b * T_SEQ + t];
    const float inv = powf(10000.0f, -(float)f / 32.0f);   // theta^(-2f/64)
    const float ang = (float)pos * inv;
    float s, c;
    sincosf(ang, &s, &c);

    const size_t off = (((size_t)(b * NH + h)) * T_SEQ + t) * DK + 2 * f;
    const float q0 = __bfloat162float(Q[off]);
    const float q1 = __bfloat162float(Q[off + 1]);
    Q[off]     = __float2bfloat16((q0 * c - q1 * s) * 0.125f);
    Q[off + 1] = __float2bfloat16((q1 * c + q0 * s) * 0.125f);
    const float k0 = __bfloat162float(K[off]);
    const float k1 = __bfloat162float(K[off + 1]);
    K[off]     = __float2bfloat16(k0 * c - k1 * s);
    K[off + 1] = __float2bfloat16(k1 * c + k0 * s);
}

// ---------------------------------------------------------------------------
// Flash attention, transposed-score formulation.
// S^T = mfma(A=K rows, B=Q rows): C col (lane&15) = Q-row -> per-lane softmax
// state, only 4 shfl per chunk (xor 16,32). P^T -> LDS -> B-operand for
// O^T = mfma(A=VT tiles, B=P). Tile map {j,63-j,64+j,127-j} balances blocks.
// ---------------------------------------------------------------------------
__global__ __launch_bounds__(256) void fattn_kernel(const __bf16* __restrict__ Q,
                                                    const __bf16* __restrict__ K,
                                                    const __bf16* __restrict__ VT,
                                                    __hip_bfloat16* __restrict__ AO)
{
    __shared__ __align__(16) __hip_bfloat16 sh_p[4][16][40];   // [wave][qi][j], pad 40

    const int wv   = threadIdx.x >> 6;
    const int lane = threadIdx.x & 63;
    const int l16  = lane & 15;
    const int quad = lane >> 4;

    const int bk = blockIdx.x;                  // 2048 blocks
    const int bh = bk >> 5;
    const int j  = bk & 31;
    const int tile = (wv == 0) ? j : (wv == 1) ? 63 - j : (wv == 2) ? 64 + j : 127 - j;
    const int b = bh >> 4, h = bh & (NH - 1);
    const int qi0 = tile * 16;

    // Q fragments (B-operand): lane l16 = Q-row, regs k = quad*8 + jj (+32)
    const __bf16* Qp = Q + ((size_t)bh * T_SEQ + qi0 + l16) * DK + quad * 8;
    const bf16x8 qb0 = *(const bf16x8*)Qp;
    const bf16x8 qb1 = *(const bf16x8*)(Qp + 32);

    const __bf16* Kb = K  + (size_t)bh * T_SEQ * DK;
    const __bf16* Vb = VT + (size_t)bh * DK * T_SEQ;

    floatx4 o0 = {0,0,0,0}, o1 = {0,0,0,0}, o2 = {0,0,0,0}, o3 = {0,0,0,0};
    float m_run = -1e30f;
    float l_run = 0.f;

    const int nch = (qi0 + 47) >> 5;            // 32-wide KV chunks, causal

    // preload K fragments for chunk 0 (A-operand: lane l16 = KV row)
    const __bf16* kp0 = Kb + (size_t)l16 * DK + quad * 8;
    bf16x8 ka0l = *(const bf16x8*)(kp0);
    bf16x8 ka0h = *(const bf16x8*)(kp0 + 32);
    bf16x8 ka1l = *(const bf16x8*)(kp0 + 16 * DK);
    bf16x8 ka1h = *(const bf16x8*)(kp0 + 16 * DK + 32);

    for (int c = 0; c < nch; ++c) {
        const int tj0 = c * 32;

        floatx4 s0 = {0,0,0,0}, s1 = {0,0,0,0};
        s0 = __builtin_amdgcn_mfma_f32_16x16x32_bf16(ka0l, qb0, s0, 0, 0, 0);
        s0 = __builtin_amdgcn_mfma_f32_16x16x32_bf16(ka0h, qb1, s0, 0, 0, 0);
        s1 = __builtin_amdgcn_mfma_f32_16x16x32_bf16(ka1l, qb0, s1, 0, 0, 0);
        s1 = __builtin_amdgcn_mfma_f32_16x16x32_bf16(ka1h, qb1, s1, 0, 0, 0);

        // prefetch next chunk's K fragments (clamped; overlaps softmax below)
        {
            const int cn = (c + 1 < nch) ? c + 1 : c;
            const __bf16* kpn = Kb + ((size_t)(cn * 32) + l16) * DK + quad * 8;
            ka0l = *(const bf16x8*)(kpn);
            ka0h = *(const bf16x8*)(kpn + 32);
            ka1l = *(const bf16x8*)(kpn + 16 * DK);
            ka1h = *(const bf16x8*)(kpn + 16 * DK + 32);
        }

        // V fragments for current chunk (A-operand of O^T): lane l16 = d-in-group
        const __bf16* vp = Vb + (size_t)l16 * T_SEQ + tj0 + quad * 8;
        const bf16x8 va0 = *(const bf16x8*)(vp);
        const bf16x8 va1 = *(const bf16x8*)(vp + 16 * T_SEQ);
        const bf16x8 va2 = *(const bf16x8*)(vp + 32 * T_SEQ);
        const bf16x8 va3 = *(const bf16x8*)(vp + 48 * T_SEQ);

        // per-lane softmax: lane l16 = Q-row qi, holds cols tj0+quad*4+r (+16)
        const int qi = qi0 + l16;
        float v0[4], v1[4];
        float mloc = -1e30f;
        #pragma unroll
        for (int r = 0; r < 4; ++r) {
            v0[r] = (tj0 + quad * 4 + r      <= qi) ? s0[r] : -1e30f;
            v1[r] = (tj0 + 16 + quad * 4 + r <= qi) ? s1[r] : -1e30f;
            mloc = fmaxf(mloc, fmaxf(v0[r], v1[r]));
        }
        mloc = fmaxf(mloc, __shfl_xor(mloc, 16));
        mloc = fmaxf(mloc, __shfl_xor(mloc, 32));
        const float nm = fmaxf(m_run, mloc);
        const float al = __expf(m_run - nm);
        m_run = nm;

        float p0[4], p1[4];
        float ls = 0.f;
        #pragma unroll
        for (int r = 0; r < 4; ++r) {
            p0[r] = __expf(v0[r] - nm);
            p1[r] = __expf(v1[r] - nm);
            ls += p0[r] + p1[r];
        }
        ls += __shfl_xor(ls, 16);
        ls += __shfl_xor(ls, 32);
        l_run = l_run * al + ls;

        // rescale O (al is per-lane scalar = per Q-row)
        #pragma unroll
        for (int r = 0; r < 4; ++r) {
            o0[r] *= al; o1[r] *= al; o2[r] *= al; o3[r] *= al;
        }

        // P^T -> LDS: shp[qi][j]; lane writes rows l16, cols quad*4..+3 (+16)
        bf16x4 w0, w1;
        #pragma unroll
        for (int r = 0; r < 4; ++r) { w0[r] = (__bf16)p0[r]; w1[r] = (__bf16)p1[r]; }
        *(bf16x4*)&sh_p[wv][l16][quad * 4]      = w0;
        *(bf16x4*)&sh_p[wv][l16][16 + quad * 4] = w1;
        asm volatile("s_waitcnt lgkmcnt(0)" ::: "memory");
        __builtin_amdgcn_wave_barrier();

        // P as B-operand: lane l16 = Q-row, k = quad*8 + jj
        const bf16x8 pb = *(const bf16x8*)&sh_p[wv][l16][quad * 8];

        o0 = __builtin_amdgcn_mfma_f32_16x16x32_bf16(va0, pb, o0, 0, 0, 0);
        o1 = __builtin_amdgcn_mfma_f32_16x16x32_bf16(va1, pb, o1, 0, 0, 0);
        o2 = __builtin_amdgcn_mfma_f32_16x16x32_bf16(va2, pb, o2, 0, 0, 0);
        o3 = __builtin_amdgcn_mfma_f32_16x16x32_bf16(va3, pb, o3, 0, 0, 0);
        __builtin_amdgcn_wave_barrier();
    }

    // epilogue: lane holds O[qi=qi0+l16][d = g*16 + quad*4 + r]
    const float inv = 1.0f / l_run;
    __hip_bfloat16* Ao = AO + ((size_t)b * T_SEQ + qi0 + l16) * DM + h * 64 + quad * 4;
    bf16x4 e;
    #pragma unroll
    for (int r = 0; r < 4; ++r) e[r] = (__bf16)(o0[r] * inv);
    *(bf16x4*)(Ao +  0) = e;
    #pragma unroll
    for (int r = 0; r < 4; ++r) e[r] = (__bf16)(o1[r] * inv);
    *(bf16x4*)(Ao + 16) = e;
    #pragma unroll
    for (int r = 0; r < 4; ++r) e[r] = (__bf16)(o2[r] * inv);
    *(bf16x4*)(Ao + 32) = e;
    #pragma unroll
    for (int r = 0; r < 4; ++r) e[r] = (__bf16)(o3[r] * inv);
    *(bf16x4*)(Ao + 48) = e;
}

extern "C" void kernel_launch(void* const* d_in, const int* in_sizes, int n_in,
                              void* d_out, int out_size, void* d_ws, size_t ws_size,
                              hipStream_t stream) {
    const float* x  = (const float*)d_in[0];
    const int*   tp = (const int*)d_in[1];
    const float* wq = (const float*)d_in[2];
    const float* wk = (const float*)d_in[3];
    const float* wv = (const float*)d_in[4];
    const float* wo = (const float*)d_in[5];

    char* ws = (char*)d_ws;
    const size_t XSZ = (size_t)B_SZ * T_SEQ * DM * 2;       // 16.78 MB
    const size_t WSZ = (size_t)DM * DM * 2;                 // 2 MB
    const size_t SZ  = (size_t)B_SZ * NH * T_SEQ * DK * 2;  // 16.78 MB

    __hip_bfloat16* xb  = (__hip_bfloat16*)(ws);
    __hip_bfloat16* wqb = (__hip_bfloat16*)(ws + XSZ);
    __hip_bfloat16* wkb = (__hip_bfloat16*)(ws + XSZ + WSZ);
    __hip_bfloat16* wvb = (__hip_bfloat16*)(ws + XSZ + 2 * WSZ);
    __hip_bfloat16* wob = (__hip_bfloat16*)(ws + XSZ + 3 * WSZ);
    __hip_bfloat16* Q   = (__hip_bfloat16*)(ws + XSZ + 4 * WSZ);
    __hip_bfloat16* K   = (__hip_bfloat16*)(ws + XSZ + 4 * WSZ + SZ);
    __hip_bfloat16* VT  = (__hip_bfloat16*)(ws + XSZ + 4 * WSZ + 2 * SZ);
    __hip_bfloat16* AO  = (__hip_bfloat16*)(ws + XSZ + 4 * WSZ + 3 * SZ);
    float* out = (float*)d_out;

    // 1. canonicalize fp32 inputs to bf16
    convert_kernel<<<2048, 256, 0, stream>>>(x,  xb,  B_SZ * T_SEQ * DM);
    convert_kernel<<<512,  256, 0, stream>>>(wq, wqb, DM * DM);
    convert_kernel<<<512,  256, 0, stream>>>(wk, wkb, DM * DM);
    convert_kernel<<<512,  256, 0, stream>>>(wv, wvb, DM * DM);
    convert_kernel<<<512,  256, 0, stream>>>(wo, wob, DM * DM);

    // 2. projections: Q,K -> [B][H][T][DK]; V -> transposed [B][H][DK][T]
    gemm16_kernel<<<8192, 256, 0, stream>>>((const __bf16*)xb, (const __bf16*)wqb, Q,  nullptr, 1);
    gemm16_kernel<<<8192, 256, 0, stream>>>((const __bf16*)xb, (const __bf16*)wkb, K,  nullptr, 1);
    gemm16_kernel<<<8192, 256, 0, stream>>>((const __bf16*)xb, (const __bf16*)wvb, VT, nullptr, 2);

    // 3. RoPE in place on Q (scaled by 1/8), K
    rope_kernel<<<16384, 256, 0, stream>>>(Q, K, tp);

    // 4. flash attention -> AO [B][T][DM] (bf16)
    fattn_kernel<<<2048, 256, 0, stream>>>((const __bf16*)Q, (const __bf16*)K,
                                           (const __bf16*)VT, AO);

    // 5. O projection -> d_out (fp32)
    gemm16_kernel<<<8192, 256, 0, stream>>>((const __bf16*)AO, (const __bf16*)wob, nullptr, out, 0);
}

// Round 7
// 447.333 us; speedup vs baseline: 8.7118x; 2.8533x over previous
//
#include <hip/hip_runtime.h>
#include <hip/hip_bf16.h>

#define B_SZ 4
#define T_SEQ 2048
#define NH 16
#define DK 64
#define DM 1024

typedef __bf16 bf16x8 __attribute__((ext_vector_type(8)));
typedef __bf16 bf16x4 __attribute__((ext_vector_type(4)));
typedef float floatx4 __attribute__((ext_vector_type(4)));

__device__ __forceinline__ void gl2lds16(const __bf16* g, __bf16* l) {
    __builtin_amdgcn_global_load_lds(
        (const __attribute__((address_space(1))) unsigned int*)g,
        (__attribute__((address_space(3))) unsigned int*)l, 16, 0, 0);
}

// fp32 -> bf16, vectorized x4
__global__ __launch_bounds__(256) void convert4_kernel(const float* __restrict__ src,
                                                       __hip_bfloat16* __restrict__ dst,
                                                       int n4)
{
    const int i = blockIdx.x * 256 + threadIdx.x;
    if (i >= n4) return;
    const float4 v = ((const float4*)src)[i];
    bf16x4 e = { (__bf16)v.x, (__bf16)v.y, (__bf16)v.z, (__bf16)v.w };
    *(bf16x4*)&dst[i * 4] = e;
}

// all four weight matrices (contiguous dst), vectorized x4
__global__ __launch_bounds__(256) void convertw_kernel(const float* __restrict__ w0,
                                                       const float* __restrict__ w1,
                                                       const float* __restrict__ w2,
                                                       const float* __restrict__ w3,
                                                       __hip_bfloat16* __restrict__ dst)
{
    const int i = blockIdx.x * 256 + threadIdx.x;      // 4 * 1M / 4 = 1M threads
    const int seg = i >> 18;                            // 256K vec4 per weight
    const int off = i & 262143;
    const float* src = (seg == 0) ? w0 : (seg == 1) ? w1 : (seg == 2) ? w2 : w3;
    const float4 v = ((const float4*)src)[off];
    bf16x4 e = { (__bf16)v.x, (__bf16)v.y, (__bf16)v.z, (__bf16)v.w };
    *(bf16x4*)&dst[i * 4] = e;
}

// ---------------------------------------------------------------------------
// m97-style 128x128 GEMM mainloop: C[m][n] = sum_k A[m][k]*W[n][k], K=1024.
// BK=32, global_load_lds width 16, 4 waves x (4x4 of 16x16x32 MFMA).
// ---------------------------------------------------------------------------
__device__ __forceinline__ void gemm_mainloop(const __bf16* __restrict__ A,
                                              const __bf16* __restrict__ W,
                                              int m0, int n0,
                                              __bf16* As, __bf16* Bs,
                                              floatx4 acc[4][4])
{
    const int tid  = threadIdx.x;
    const int wv_  = tid >> 6;
    const int lane = tid & 63;
    const int l16  = lane & 15;
    const int quad = lane >> 4;

    // staging: thread covers rows p*64 + wv_*16 + (lane>>2), cols (lane&3)*8
    const int srow = wv_ * 16 + (lane >> 2);
    const int scol = (lane & 3) * 8;
    const __bf16* ag = A + (size_t)(m0 + srow) * 1024 + scol;
    const __bf16* bg = W + (size_t)(n0 + srow) * 1024 + scol;
    __bf16* al = As + wv_ * 512;    // HW adds lane*16B; rows 64-apart -> +2048 el
    __bf16* bl = Bs + wv_ * 512;

    const int mi0 = (wv_ >> 1) * 64;
    const int ni0 = (wv_ & 1) * 64;

    for (int k0 = 0; k0 < 1024; k0 += 32) {
        __syncthreads();
        gl2lds16(ag + k0,             al);
        gl2lds16(ag + 64 * 1024 + k0, al + 2048);
        gl2lds16(bg + k0,             bl);
        gl2lds16(bg + 64 * 1024 + k0, bl + 2048);
        __syncthreads();

        bf16x8 af[4], bfr[4];
        #pragma unroll
        for (int i = 0; i < 4; ++i)
            af[i] = *(const bf16x8*)(As + (mi0 + i * 16 + l16) * 32 + quad * 8);
        #pragma unroll
        for (int j = 0; j < 4; ++j)
            bfr[j] = *(const bf16x8*)(Bs + (ni0 + j * 16 + l16) * 32 + quad * 8);
        #pragma unroll
        for (int i = 0; i < 4; ++i)
            #pragma unroll
            for (int j = 0; j < 4; ++j)
                acc[i][j] = __builtin_amdgcn_mfma_f32_16x16x32_bf16(af[i], bfr[j], acc[i][j], 0, 0, 0);
    }
}

// Fused QKV projection. grid (24, 64): x = mat*8 + ntile, y = mtile.
// Q,K -> [bh][t][64]; V -> transposed [bh][64][t].
__global__ __launch_bounds__(256) void qkv_gemm_kernel(const __bf16* __restrict__ A,
                                                       const __bf16* __restrict__ Wq,
                                                       const __bf16* __restrict__ Wk,
                                                       const __bf16* __restrict__ Wv,
                                                       __hip_bfloat16* __restrict__ Q,
                                                       __hip_bfloat16* __restrict__ Kd,
                                                       __hip_bfloat16* __restrict__ VT)
{
    __shared__ __align__(16) __bf16 As[128 * 32];
    __shared__ __align__(16) __bf16 Bs[128 * 32];

    const int nt  = blockIdx.x;
    const int mt  = blockIdx.y;
    const int mat = nt >> 3;
    const int n0  = (nt & 7) * 128;
    const int m0  = mt * 128;
    const __bf16* W = (mat == 0) ? Wq : (mat == 1) ? Wk : Wv;

    floatx4 acc[4][4] = {};
    gemm_mainloop(A, W, m0, n0, As, Bs, acc);

    const int wv_  = threadIdx.x >> 6;
    const int lane = threadIdx.x & 63;
    const int l16  = lane & 15;
    const int quad = lane >> 4;
    const int mi0  = (wv_ >> 1) * 64;
    const int ni0  = (wv_ & 1) * 64;

    if (mat < 2) {
        __hip_bfloat16* dst = (mat == 0) ? Q : Kd;
        #pragma unroll
        for (int i = 0; i < 4; ++i) {
            #pragma unroll
            for (int j = 0; j < 4; ++j) {
                const int col = n0 + ni0 + j * 16 + l16;
                const int h = col >> 6, d = col & 63;
                #pragma unroll
                for (int r = 0; r < 4; ++r) {
                    const int row = m0 + mi0 + i * 16 + quad * 4 + r;
                    const int b = row >> 11, t = row & (T_SEQ - 1);
                    dst[(((size_t)(b * NH + h)) * T_SEQ + t) * DK + d] = __float2bfloat16(acc[i][j][r]);
                }
            }
        }
    } else {
        #pragma unroll
        for (int i = 0; i < 4; ++i) {
            const int row0 = m0 + mi0 + i * 16 + quad * 4;
            const int b = row0 >> 11, t0 = row0 & (T_SEQ - 1);
            #pragma unroll
            for (int j = 0; j < 4; ++j) {
                const int col = n0 + ni0 + j * 16 + l16;
                const int h = col >> 6, d = col & 63;
                bf16x4 e;
                #pragma unroll
                for (int r = 0; r < 4; ++r) e[r] = (__bf16)acc[i][j][r];
                *(bf16x4*)&VT[(((size_t)(b * NH + h)) * DK + d) * T_SEQ + t0] = e;
            }
        }
    }
}

// O projection -> fp32 d_out. grid (8, 64).
__global__ __launch_bounds__(256) void oproj_gemm_kernel(const __bf16* __restrict__ A,
                                                         const __bf16* __restrict__ W,
                                                         float* __restrict__ out)
{
    __shared__ __align__(16) __bf16 As[128 * 32];
    __shared__ __align__(16) __bf16 Bs[128 * 32];

    const int n0 = blockIdx.x * 128;
    const int m0 = blockIdx.y * 128;

    floatx4 acc[4][4] = {};
    gemm_mainloop(A, W, m0, n0, As, Bs, acc);

    const int wv_  = threadIdx.x >> 6;
    const int lane = threadIdx.x & 63;
    const int l16  = lane & 15;
    const int quad = lane >> 4;
    const int mi0  = (wv_ >> 1) * 64;
    const int ni0  = (wv_ & 1) * 64;

    #pragma unroll
    for (int i = 0; i < 4; ++i) {
        #pragma unroll
        for (int j = 0; j < 4; ++j) {
            const int col = n0 + ni0 + j * 16 + l16;
            #pragma unroll
            for (int r = 0; r < 4; ++r) {
                const int row = m0 + mi0 + i * 16 + quad * 4 + r;
                out[(size_t)row * DM + col] = acc[i][j][r];
            }
        }
    }
}

// In-place RoPE on Q and K, layout [B][NH][T][DK]. Q additionally scaled by 1/8.
__global__ __launch_bounds__(256) void rope_kernel(__hip_bfloat16* __restrict__ Q,
                                                   __hip_bfloat16* __restrict__ K,
                                                   const int* __restrict__ tp)
{
    const int idx = blockIdx.x * 256 + threadIdx.x;   // 4*16*2048*32 = 4194304
    const int f = idx & 31;
    const int t = (idx >> 5) & (T_SEQ - 1);
    const int h = (idx >> 16) & (NH - 1);
    const int b = idx >> 20;

    const int pos = tp[b * T_SEQ + t];
    // theta^(-f/32) = exp2(-f * log2(10000)/32)
    const float inv = exp2f(-(float)f * 0.41524101186092029f);
    const float ang = (float)pos * inv;
    float s, c;
    sincosf(ang, &s, &c);

    const size_t off = (((size_t)(b * NH + h)) * T_SEQ + t) * DK + 2 * f;
    const float q0 = __bfloat162float(Q[off]);
    const float q1 = __bfloat162float(Q[off + 1]);
    Q[off]     = __float2bfloat16((q0 * c - q1 * s) * 0.125f);
    Q[off + 1] = __float2bfloat16((q1 * c + q0 * s) * 0.125f);
    const float k0 = __bfloat162float(K[off]);
    const float k1 = __bfloat162float(K[off + 1]);
    K[off]     = __float2bfloat16(k0 * c - k1 * s);
    K[off + 1] = __float2bfloat16(k1 * c + k0 * s);
}

// ---------------------------------------------------------------------------
// Flash attention, transposed-score formulation (round-4 core).
// Balance fix: block bk -> waves take 4 consecutive tiles, longest blocks first.
// ---------------------------------------------------------------------------
__global__ __launch_bounds__(256) void fattn_kernel(const __bf16* __restrict__ Q,
                                                    const __bf16* __restrict__ K,
                                                    const __bf16* __restrict__ VT,
                                                    __hip_bfloat16* __restrict__ AO)
{
    __shared__ __align__(16) __hip_bfloat16 sh_p[4][16][40];

    const int wv   = threadIdx.x >> 6;
    const int lane = threadIdx.x & 63;
    const int l16  = lane & 15;
    const int quad = lane >> 4;

    const int bk = blockIdx.x;                  // 2048 blocks
    const int ig = bk >> 6;                     // 0..31 (duration group, long first)
    const int bh = bk & 63;
    const int tile = 127 - (ig * 4 + wv);
    const int b = bh >> 4, h = bh & (NH - 1);
    const int qi0 = tile * 16;

    const __bf16* Qp = Q + ((size_t)bh * T_SEQ + qi0 + l16) * DK + quad * 8;
    const bf16x8 qb0 = *(const bf16x8*)Qp;
    const bf16x8 qb1 = *(const bf16x8*)(Qp + 32);

    const __bf16* Kb = K  + (size_t)bh * T_SEQ * DK;
    const __bf16* Vb = VT + (size_t)bh * DK * T_SEQ;

    floatx4 o0 = {0,0,0,0}, o1 = {0,0,0,0}, o2 = {0,0,0,0}, o3 = {0,0,0,0};
    float m_run = -1e30f;
    float l_run = 0.f;

    const int nch = (qi0 + 47) >> 5;

    const __bf16* kp0 = Kb + (size_t)l16 * DK + quad * 8;
    bf16x8 ka0l = *(const bf16x8*)(kp0);
    bf16x8 ka0h = *(const bf16x8*)(kp0 + 32);
    bf16x8 ka1l = *(const bf16x8*)(kp0 + 16 * DK);
    bf16x8 ka1h = *(const bf16x8*)(kp0 + 16 * DK + 32);

    for (int c = 0; c < nch; ++c) {
        const int tj0 = c * 32;

        floatx4 s0 = {0,0,0,0}, s1 = {0,0,0,0};
        s0 = __builtin_amdgcn_mfma_f32_16x16x32_bf16(ka0l, qb0, s0, 0, 0, 0);
        s0 = __builtin_amdgcn_mfma_f32_16x16x32_bf16(ka0h, qb1, s0, 0, 0, 0);
        s1 = __builtin_amdgcn_mfma_f32_16x16x32_bf16(ka1l, qb0, s1, 0, 0, 0);
        s1 = __builtin_amdgcn_mfma_f32_16x16x32_bf16(ka1h, qb1, s1, 0, 0, 0);

        {
            const int cn = (c + 1 < nch) ? c + 1 : c;
            const __bf16* kpn = Kb + ((size_t)(cn * 32) + l16) * DK + quad * 8;
            ka0l = *(const bf16x8*)(kpn);
            ka0h = *(const bf16x8*)(kpn + 32);
            ka1l = *(const bf16x8*)(kpn + 16 * DK);
            ka1h = *(const bf16x8*)(kpn + 16 * DK + 32);
        }

        const __bf16* vp = Vb + (size_t)l16 * T_SEQ + tj0 + quad * 8;
        const bf16x8 va0 = *(const bf16x8*)(vp);
        const bf16x8 va1 = *(const bf16x8*)(vp + 16 * T_SEQ);
        const bf16x8 va2 = *(const bf16x8*)(vp + 32 * T_SEQ);
        const bf16x8 va3 = *(const bf16x8*)(vp + 48 * T_SEQ);

        const int qi = qi0 + l16;
        float v0[4], v1[4];
        float mloc = -1e30f;
        #pragma unroll
        for (int r = 0; r < 4; ++r) {
            v0[r] = (tj0 + quad * 4 + r      <= qi) ? s0[r] : -1e30f;
            v1[r] = (tj0 + 16 + quad * 4 + r <= qi) ? s1[r] : -1e30f;
            mloc = fmaxf(mloc, fmaxf(v0[r], v1[r]));
        }
        mloc = fmaxf(mloc, __shfl_xor(mloc, 16));
        mloc = fmaxf(mloc, __shfl_xor(mloc, 32));
        const float nm = fmaxf(m_run, mloc);
        const float al = __expf(m_run - nm);
        m_run = nm;

        float p0[4], p1[4];
        float ls = 0.f;
        #pragma unroll
        for (int r = 0; r < 4; ++r) {
            p0[r] = __expf(v0[r] - nm);
            p1[r] = __expf(v1[r] - nm);
            ls += p0[r] + p1[r];
        }
        ls += __shfl_xor(ls, 16);
        ls += __shfl_xor(ls, 32);
        l_run = l_run * al + ls;

        #pragma unroll
        for (int r = 0; r < 4; ++r) {
            o0[r] *= al; o1[r] *= al; o2[r] *= al; o3[r] *= al;
        }

        bf16x4 w0, w1;
        #pragma unroll
        for (int r = 0; r < 4; ++r) { w0[r] = (__bf16)p0[r]; w1[r] = (__bf16)p1[r]; }
        *(bf16x4*)&sh_p[wv][l16][quad * 4]      = w0;
        *(bf16x4*)&sh_p[wv][l16][16 + quad * 4] = w1;
        asm volatile("s_waitcnt lgkmcnt(0)" ::: "memory");
        __builtin_amdgcn_wave_barrier();

        const bf16x8 pb = *(const bf16x8*)&sh_p[wv][l16][quad * 8];

        o0 = __builtin_amdgcn_mfma_f32_16x16x32_bf16(va0, pb, o0, 0, 0, 0);
        o1 = __builtin_amdgcn_mfma_f32_16x16x32_bf16(va1, pb, o1, 0, 0, 0);
        o2 = __builtin_amdgcn_mfma_f32_16x16x32_bf16(va2, pb, o2, 0, 0, 0);
        o3 = __builtin_amdgcn_mfma_f32_16x16x32_bf16(va3, pb, o3, 0, 0, 0);
        __builtin_amdgcn_wave_barrier();
    }

    const float inv = 1.0f / l_run;
    __hip_bfloat16* Ao = AO + ((size_t)b * T_SEQ + qi0 + l16) * DM + h * 64 + quad * 4;
    bf16x4 e;
    #pragma unroll
    for (int r = 0; r < 4; ++r) e[r] = (__bf16)(o0[r] * inv);
    *(bf16x4*)(Ao +  0) = e;
    #pragma unroll
    for (int r = 0; r < 4; ++r) e[r] = (__bf16)(o1[r] * inv);
    *(bf16x4*)(Ao + 16) = e;
    #pragma unroll
    for (int r = 0; r < 4; ++r) e[r] = (__bf16)(o2[r] * inv);
    *(bf16x4*)(Ao + 32) = e;
    #pragma unroll
    for (int r = 0; r < 4; ++r) e[r] = (__bf16)(o3[r] * inv);
    *(bf16x4*)(Ao + 48) = e;
}

extern "C" void kernel_launch(void* const* d_in, const int* in_sizes, int n_in,
                              void* d_out, int out_size, void* d_ws, size_t ws_size,
                              hipStream_t stream) {
    const float* x  = (const float*)d_in[0];
    const int*   tp = (const int*)d_in[1];
    const float* wq = (const float*)d_in[2];
    const float* wk = (const float*)d_in[3];
    const float* wv = (const float*)d_in[4];
    const float* wo = (const float*)d_in[5];

    char* ws = (char*)d_ws;
    const size_t XSZ = (size_t)B_SZ * T_SEQ * DM * 2;       // 16.78 MB
    const size_t WSZ = (size_t)DM * DM * 2;                 // 2 MB
    const size_t SZ  = (size_t)B_SZ * NH * T_SEQ * DK * 2;  // 16.78 MB

    __hip_bfloat16* xb  = (__hip_bfloat16*)(ws);
    __hip_bfloat16* wqb = (__hip_bfloat16*)(ws + XSZ);       // wq..wo contiguous
    __hip_bfloat16* wkb = (__hip_bfloat16*)(ws + XSZ + WSZ);
    __hip_bfloat16* wvb = (__hip_bfloat16*)(ws + XSZ + 2 * WSZ);
    __hip_bfloat16* wob = (__hip_bfloat16*)(ws + XSZ + 3 * WSZ);
    __hip_bfloat16* Q   = (__hip_bfloat16*)(ws + XSZ + 4 * WSZ);
    __hip_bfloat16* K   = (__hip_bfloat16*)(ws + XSZ + 4 * WSZ + SZ);
    __hip_bfloat16* VT  = (__hip_bfloat16*)(ws + XSZ + 4 * WSZ + 2 * SZ);
    __hip_bfloat16* AO  = (__hip_bfloat16*)(ws + XSZ + 4 * WSZ + 3 * SZ);
    float* out = (float*)d_out;

    // 1. canonicalize fp32 inputs to bf16 (x + all four weights)
    convert4_kernel<<<8192, 256, 0, stream>>>(x, xb, B_SZ * T_SEQ * DM / 4);
    convertw_kernel<<<4096, 256, 0, stream>>>(wq, wk, wv, wo, wqb);

    // 2. fused QKV projection: Q,K -> [bh][t][64]; V -> [bh][64][t]
    qkv_gemm_kernel<<<dim3(24, 64), 256, 0, stream>>>(
        (const __bf16*)xb, (const __bf16*)wqb, (const __bf16*)wkb, (const __bf16*)wvb,
        Q, K, VT);

    // 3. RoPE in place on Q (scaled by 1/8), K
    rope_kernel<<<16384, 256, 0, stream>>>(Q, K, tp);

    // 4. flash attention -> AO [B][T][DM] (bf16)
    fattn_kernel<<<2048, 256, 0, stream>>>((const __bf16*)Q, (const __bf16*)K,
                                           (const __bf16*)VT, AO);

    // 5. O projection -> d_out (fp32)
    oproj_gemm_kernel<<<dim3(8, 64), 256, 0, stream>>>(
        (const __bf16*)AO, (const __bf16*)wob, out);
}